// Round 9
// baseline (313.534 us; speedup 1.0000x reference)
//
#include <hip/hip_runtime.h>
#include <hip/hip_bf16.h>
#include <hip/hip_fp8.h>
#include <math.h>

// out[b] = logsumexp_v( relu(vectors[cs[b]]@W1+b1) @ W2 + b2 ) - logit[b, v2s[ws[b]]]
// GEMM2+LSE in MX-scaled fp8 e4m3 K=128 (2x bf16 rate, unit scales); fixed-max
// exp2 LSE (logits bounded ~|4.5|); target dot also fp8 (same quantized operands).
//
// R9: R8 refuted LDS-BW-bound (2nd time); k3 is issue-bound: MFMA 46% + VALU 41%
// ~= 87% of SIMD timeline, and ~165/247 VALU instrs/wave/chunk are OVERHEAD
// (runtime-`cur` address recompute each chunk). Fix: unroll chunk loop x2 with
// compile-time buffer pointers -> LDS addresses loop-invariant, LICM-hoisted.
// Also: kprep split so k1 (gather-bound) co-runs with W2 quant (stream-bound)
// in one merged grid; W2F dropped.

typedef __bf16 bf16x8 __attribute__((ext_vector_type(8)));
typedef float f32x4 __attribute__((ext_vector_type(4)));
typedef int i32x4 __attribute__((ext_vector_type(4)));
typedef int i32x8 __attribute__((ext_vector_type(8)));

#define B_N 8192
#define D_N 300
#define K1K 320                // D padded to 10 k-steps of 32
#define H_N 512
#define V_N 20000
#define V_PAD 20480            // 16 splits x 40 chunks x 32 cols
#define NSPLIT 16
#define SPLIT_V 1280           // cols per split
#define NCH 40                 // chunks per split (even -> clean unroll-2)
#define ROWS_BLK 128           // 4 waves x 32 rows (2 m-tiles each)
#define CHUNK_BYTES 16384      // 32 cols x 512 k x 1B (fp8)

#define OFF_PART (8388608u)                        // 16*8192*8 = 1 MB
#define OFF_W1T  (OFF_PART + 16u*8192u*8u)
#define OFF_B2L  (OFF_W1T + 512u*320u*2u)
#define OFF_H8   (OFF_B2L + 20480u*4u)             // 8192*512 = 4 MB
#define OFF_W2T8 (OFF_H8 + 8192u*512u)             // 20480*512 = 10.5 MB

#define SCALE1 0x7F7F7F7F      // E8M0 127 = 2^0 = 1.0 in every byte
#define LOG2E  1.4426950408889634f

__device__ inline unsigned short f2bf(float f) {
  __hip_bfloat16 h = __float2bfloat16(f);
  return *reinterpret_cast<unsigned short*>(&h);
}

__device__ inline unsigned char f2fp8(float f) {
  __hip_fp8_e4m3 q(f);
  return (unsigned char)q.__x;
}

// pack 4 floats -> 4 fp8 e4m3 bytes; HW packed convert where available
__device__ inline unsigned int pk4_fp8(float a, float b, float c, float d) {
#if __has_builtin(__builtin_amdgcn_cvt_pk_fp8_f32)
  int v = 0;
  v = __builtin_amdgcn_cvt_pk_fp8_f32(a, b, v, false);  // bytes 0,1
  v = __builtin_amdgcn_cvt_pk_fp8_f32(c, d, v, true);   // bytes 2,3
  return (unsigned int)v;
#else
  return (unsigned int)f2fp8(a) | ((unsigned int)f2fp8(b) << 8) |
         ((unsigned int)f2fp8(c) << 16) | ((unsigned int)f2fp8(d) << 24);
#endif
}

__device__ inline float fp82f(unsigned char b) {
  __hip_fp8_e4m3 q; q.__x = b;
  return (float)q;
}

__device__ __forceinline__ void gl16(const void* g, void* l) {
  __builtin_amdgcn_global_load_lds(
      (const __attribute__((address_space(1))) void*)g,
      (__attribute__((address_space(3))) void*)l, 16, 0, 0);
}

// ---------------- KPREP_A: W1 transpose (blocks 0..39), b2l (40..119) ----------------
__global__ __launch_bounds__(256) void kprep_a(
    const float* __restrict__ W1, unsigned int* __restrict__ W1Tu,
    const float* __restrict__ b2, float* __restrict__ b2l)
{
  __shared__ float tile[64][65];
  const int bid = blockIdx.x;
  const int tid = threadIdx.x;
  if (bid < 40) {
    // ---- W1 [300][512] f32 -> W1T [512][320] bf16 (k-pad zeros)
    const int n0 = (bid & 7) * 64;   // over H=512
    const int k0 = (bid >> 3) * 64;  // over 320
    #pragma unroll
    for (int it = 0; it < 16; ++it) {
      int idx = it * 256 + tid;
      int i = idx >> 6;     // k-local
      int j = idx & 63;     // n-local
      float v = 0.f;
      if (k0 + i < D_N) v = W1[(size_t)(k0 + i) * H_N + n0 + j];
      tile[i][j] = v;
    }
    __syncthreads();
    #pragma unroll
    for (int it = 0; it < 8; ++it) {
      int idx = it * 256 + tid;
      int nl = idx >> 5;    // 0..63
      int k = (idx & 31) * 2;
      unsigned int lo = f2bf(tile[k][nl]);
      unsigned int hi = f2bf(tile[k + 1][nl]);
      W1Tu[((size_t)(n0 + nl) * K1K + k0 + k) >> 1] = (hi << 16) | lo;
    }
  } else {
    // ---- b2l[i] = i<V_N ? b2[i]*log2e : -3e37 (log2-domain bias, pad -> exp2==0)
    int i = (bid - 40) * 256 + tid;
    if (i < V_PAD) b2l[i] = (i < V_N) ? b2[i] * LOG2E : -3.0e37f;
  }
}

// ---------------- KPREP_B: merged k1 (blocks 0..511) + W2 quant (512..3071) ----------
// k1 (gather/MFMA, latency-bound) and W2 quant (stream-bound) are independent;
// co-scheduling them fills each other's stalls.
__global__ __launch_bounds__(256) void kprep_b(
    const int* __restrict__ cs, const float* __restrict__ vectors,
    const unsigned short* __restrict__ W1T, const float* __restrict__ b1,
    unsigned char* __restrict__ h8Out,
    const float* __restrict__ W2, unsigned long long* __restrict__ W2T8u)
{
  __shared__ float tile[64][65];
  __shared__ __align__(16) unsigned short vca[16][328];
  __shared__ int rowIdx[16];
  const int bid = blockIdx.x;
  const int tid = threadIdx.x;

  if (bid >= 512) {
    // ---- W2 [512][20000] f32 -> W2T8 [20480][512] fp8 (pad rows 0),
    //      PRE-SWIZZLED 16B: byte (n*512 + (k ^ ((n&15)<<4))) holds logical (n,k)
    const int wb = bid - 512;
    const int n0 = (wb >> 3) * 64;
    const int k0 = (wb & 7) * 64;
    #pragma unroll
    for (int it = 0; it < 4; ++it) {
      int idx = it * 256 + tid;        // 0..1023
      int i = idx >> 4;                // k-local 0..63
      int j4 = (idx & 15) * 4;         // n-local 0,4,..,60
      const float* src = &W2[(size_t)(k0 + i) * V_N + n0 + j4];
      float4 v = make_float4(0.f, 0.f, 0.f, 0.f);
      if (n0 + j4 + 3 < V_N) {
        v = *(const float4*)src;
      } else {
        if (n0 + j4 + 0 < V_N) v.x = src[0];
        if (n0 + j4 + 1 < V_N) v.y = src[1];
        if (n0 + j4 + 2 < V_N) v.z = src[2];
        if (n0 + j4 + 3 < V_N) v.w = src[3];
      }
      tile[i][j4 + 0] = v.x; tile[i][j4 + 1] = v.y;
      tile[i][j4 + 2] = v.z; tile[i][j4 + 3] = v.w;
    }
    __syncthreads();
    #pragma unroll
    for (int it = 0; it < 2; ++it) {
      int idx = it * 256 + tid;
      int nl = idx >> 3;          // 0..63
      int g8 = (idx & 7) * 8;     // k-local group start
      int n = n0 + nl;
      unsigned int lo = pk4_fp8(tile[g8 + 0][nl], tile[g8 + 1][nl],
                                tile[g8 + 2][nl], tile[g8 + 3][nl]);
      unsigned int hi = pk4_fp8(tile[g8 + 4][nl], tile[g8 + 5][nl],
                                tile[g8 + 6][nl], tile[g8 + 7][nl]);
      unsigned long long pack = ((unsigned long long)hi << 32) | lo;
      unsigned kk = (unsigned)(k0 + g8);
      unsigned off = ((unsigned)n * 512u + (kk ^ (((unsigned)n & 15u) << 4)));
      W2T8u[off >> 3] = pack;
    }
    return;
  }

  // ---- k1: h = relu(vectors[cs] @ W1 + b1) -> fp8, 16 rows/block ----
  const int lane = tid & 63;
  const int w = tid >> 6;          // wave 0..3 -> col band w*128
  const int l15 = lane & 15;
  const int l4 = lane >> 4;
  const int r0 = bid * 16;
  if (tid < 16) rowIdx[tid] = cs[r0 + tid];
  __syncthreads();
  // div-free staging: float4 gather + ushort4 LDS stores; 82 groups x 4 = 328
  for (int task = tid; task < 16 * 82; task += 256) {
    const int r = task & 15;
    const int g = task >> 4;           // 0..81
    const int k = g * 4;
    float4 v = make_float4(0.f, 0.f, 0.f, 0.f);
    if (k + 3 < D_N)                   // g <= 74 fully in-range
      v = *(const float4*)(vectors + (size_t)rowIdx[r] * D_N + k);
    ushort4 pk;
    pk.x = f2bf(v.x); pk.y = f2bf(v.y); pk.z = f2bf(v.z); pk.w = f2bf(v.w);
    *(ushort4*)&vca[r][k] = pk;
  }
  __syncthreads();

  bf16x8 afr[10];
  #pragma unroll
  for (int t = 0; t < 10; ++t)
    afr[t] = *(const bf16x8*)&vca[l15][t * 32 + l4 * 8];

  f32x4 acc[8];
  #pragma unroll
  for (int ct = 0; ct < 8; ++ct) acc[ct] = (f32x4){0.f, 0.f, 0.f, 0.f};

  #pragma unroll
  for (int t = 0; t < 10; ++t) {
    #pragma unroll
    for (int ct = 0; ct < 8; ++ct) {
      const int n = w * 128 + ct * 16 + l15;
      bf16x8 bfr = *(const bf16x8*)(W1T + (size_t)n * K1K + t * 32 + l4 * 8);
      acc[ct] = __builtin_amdgcn_mfma_f32_16x16x32_bf16(afr[t], bfr, acc[ct], 0, 0, 0);
    }
  }

  #pragma unroll
  for (int ct = 0; ct < 8; ++ct) {
    const int n = w * 128 + ct * 16 + l15;
    const float bb = b1[n];
    #pragma unroll
    for (int r = 0; r < 4; ++r) {
      const int row = r0 + l4 * 4 + r;
      h8Out[(size_t)row * H_N + n] = f2fp8(fmaxf(acc[ct][r] + bb, 0.f));
    }
  }
}

// stage one 16KB fp8 chunk with 256 threads: PURE LINEAR copy (global pre-swizzled)
__device__ __forceinline__ void stage_chunk(const char* g, char* l, int tid) {
  #pragma unroll
  for (int it = 0; it < 4; ++it) {
    const unsigned o = (unsigned)tid * 16 + it * 4096;
    gl16(g + o, l + o);
  }
}

// ---------------- K3: fused MX-fp8 K=128 GEMM2 + fixed-max exp2 LSE ----------------
// grid = 64 rowblocks x 16 splits = 1024 blocks = 4/CU; split = blockIdx&15 ->
// XCD-pinned. 4 waves x 32 rows (2 m-tiles, A = 64 regs) -> 16 waves/CU.
// Chunk loop UNROLLED x2 with compile-time buffer pointers: all LDS read/stage
// addresses loop-invariant -> hoisted (kills ~60 VALU instrs/wave/chunk of
// address recompute). ct-outer phases with interleaved epilogue (R3).
// one chunk body: compute chunk (c) from buffer CUR, prefetch chunk c+1 to NXT.
#define CHUNK_BODY(c, CUR, NXT, GUARD)                                         \
  {                                                                            \
    asm volatile("s_waitcnt vmcnt(0) lgkmcnt(0)" ::: "memory");                \
    __builtin_amdgcn_s_barrier();                                              \
    if (GUARD)                                                                 \
      stage_chunk(gsplit + (size_t)((c) + 1) * CHUNK_BYTES, (NXT), tid);       \
    const float b2c0 = b2s[(c) * 32 + l15];                                    \
    const float b2c1 = b2s[(c) * 32 + 16 + l15];                               \
    f32x4 acc[2][2];                                                           \
    _Pragma("unroll")                                                          \
    for (int m_ = 0; m_ < 2; ++m_)                                             \
      _Pragma("unroll")                                                        \
      for (int ct_ = 0; ct_ < 2; ++ct_)                                        \
        acc[m_][ct_] = (f32x4){0.f, 0.f, 0.f, 0.f};                            \
    /* phase 1: ct=0, full K */                                                \
    _Pragma("unroll")                                                          \
    for (int t_ = 0; t_ < 4; ++t_) {                                           \
      const char* bp = (CUR) + l15 * 512;                                      \
      i32x4 lo = *(const i32x4*)(bp + (((unsigned)(t_*128 + l4*32)) ^ swz));   \
      i32x4 hi = *(const i32x4*)(bp + (((unsigned)(t_*128 + l4*32 + 16)) ^ swz)); \
      i32x8 bfr = __builtin_shufflevector(lo, hi, 0, 1, 2, 3, 4, 5, 6, 7);     \
      __builtin_amdgcn_s_setprio(1);                                           \
      acc[0][0] = __builtin_amdgcn_mfma_scale_f32_16x16x128_f8f6f4(            \
          afr[0][t_], bfr, acc[0][0], 0, 0, 0, SCALE1, 0, SCALE1);             \
      acc[1][0] = __builtin_amdgcn_mfma_scale_f32_16x16x128_f8f6f4(            \
          afr[1][t_], bfr, acc[1][0], 0, 0, 0, SCALE1, 0, SCALE1);             \
      __builtin_amdgcn_s_setprio(0);                                           \
    }                                                                          \
    /* phase 2: ct=1 MFMAs + ct=0 epilogue interleaved */                      \
    _Pragma("unroll")                                                          \
    for (int t_ = 0; t_ < 4; ++t_) {                                           \
      const char* bp = (CUR) + (16 + l15) * 512;                               \
      i32x4 lo = *(const i32x4*)(bp + (((unsigned)(t_*128 + l4*32)) ^ swz));   \
      i32x4 hi = *(const i32x4*)(bp + (((unsigned)(t_*128 + l4*32 + 16)) ^ swz)); \
      i32x8 bfr = __builtin_shufflevector(lo, hi, 0, 1, 2, 3, 4, 5, 6, 7);     \
      __builtin_amdgcn_s_setprio(1);                                           \
      acc[0][1] = __builtin_amdgcn_mfma_scale_f32_16x16x128_f8f6f4(            \
          afr[0][t_], bfr, acc[0][1], 0, 0, 0, SCALE1, 0, SCALE1);             \
      acc[1][1] = __builtin_amdgcn_mfma_scale_f32_16x16x128_f8f6f4(            \
          afr[1][t_], bfr, acc[1][1], 0, 0, 0, SCALE1, 0, SCALE1);             \
      __builtin_amdgcn_s_setprio(0);                                           \
      _Pragma("unroll")                                                        \
      for (int r2_ = 0; r2_ < 2; ++r2_) {                                      \
        const int ri_ = t_ * 2 + r2_;                                          \
        const int m_ = ri_ >> 2, r_ = ri_ & 3;                                 \
        s_run[ri_] += __builtin_amdgcn_exp2f(fmaf(acc[m_][0][r_], LOG2E, b2c0)); \
      }                                                                        \
    }                                                                          \
    /* phase 3: ct=1 epilogue tail */                                          \
    _Pragma("unroll")                                                          \
    for (int m_ = 0; m_ < 2; ++m_)                                             \
      _Pragma("unroll")                                                        \
      for (int r_ = 0; r_ < 4; ++r_)                                           \
        s_run[m_ * 4 + r_] +=                                                  \
            __builtin_amdgcn_exp2f(fmaf(acc[m_][1][r_], LOG2E, b2c1));         \
  }

__global__ __launch_bounds__(256, 4) void k3_fused(
    const unsigned char* __restrict__ h8,   // [8192][512] fp8
    const char* __restrict__ W2T8,          // [20480][512] fp8 pre-swizzled (16B XOR)
    const float* __restrict__ b2l,          // [20480] bias*log2e (-3e37 past V_N)
    float2* __restrict__ partOut)
{
  __shared__ __align__(16) char smB[2 * CHUNK_BYTES];  // 32 KB double buffer
  __shared__ float b2s[SPLIT_V];                       // 5 KB bias slice (log2-dom)
  const int tid = threadIdx.x;
  const int lane = tid & 63;
  const int w = tid >> 6;          // wave 0..3
  const int l15 = lane & 15;
  const int l4 = lane >> 4;        // 0..3
  const int s = blockIdx.x & 15;
  const int rb = blockIdx.x >> 4;  // 0..63
  const int r0 = rb * ROWS_BLK + w * 32;
  const char* gsplit = W2T8 + (size_t)s * SPLIT_V * 512;
  const int sCol = s * SPLIT_V;

  // A fragments fp8 K=128 (16x16x128: row=l15, k=l4*32+j): 2 m-tiles x 4 k-steps
  i32x8 afr[2][4];
  #pragma unroll
  for (int m = 0; m < 2; ++m) {
    const unsigned char* ap = h8 + (size_t)(r0 + m * 16 + l15) * H_N + l4 * 32;
    #pragma unroll
    for (int t = 0; t < 4; ++t) {
      i32x4 lo = *(const i32x4*)(ap + t * 128);
      i32x4 hi = *(const i32x4*)(ap + t * 128 + 16);
      afr[m][t] = __builtin_shufflevector(lo, hi, 0, 1, 2, 3, 4, 5, 6, 7);
    }
  }

  // lane-local exp2-sum state (8 rows: 2 m-tiles x 4 regs), fixed max = 0
  float s_run[8];
  #pragma unroll
  for (int ri = 0; ri < 8; ++ri) s_run[ri] = 0.f;

  // bias slice -> LDS
  for (int i = tid; i < SPLIT_V; i += 256) b2s[i] = b2l[sCol + i];

  // prologue: stage chunk 0 into buffer 0
  stage_chunk(gsplit, smB, tid);

  const unsigned swz = (unsigned)l15 << 4;   // 16B-granular XOR (matches kprep)
  char* const buf0 = smB;
  char* const buf1 = smB + CHUNK_BYTES;

  #pragma unroll 1
  for (int c = 0; c < NCH; c += 2) {
    CHUNK_BODY(c,     buf0, buf1, true);            // even: read buf0, fill buf1
    CHUNK_BODY(c + 1, buf1, buf0, (c + 2 < NCH));   // odd:  read buf1, fill buf0
  }

  // final 16-lane sum merges (once per kernel); stored as (M=0, S)
  #pragma unroll
  for (int m = 0; m < 2; ++m)
    #pragma unroll
    for (int r = 0; r < 4; ++r) {
      int ri = m * 4 + r;
      float sc = s_run[ri];
      #pragma unroll
      for (int k = 1; k < 16; k <<= 1) sc += __shfl_xor(sc, k);
      if (l15 == 0) {
        int grow = r0 + m * 16 + l4 * 4 + r;
        partOut[(size_t)s * B_N + grow] = make_float2(0.f, sc);
      }
    }
}

// ---------------- K45: fp8 target dot (same quantized operands as LSE) + combine ----------------
__global__ __launch_bounds__(256) void k45_final(
    const unsigned char* __restrict__ h8, const char* __restrict__ W2T8,
    const float* __restrict__ b2, const int* __restrict__ wsIdx,
    const int* __restrict__ v2s, const float2* __restrict__ part,
    float* __restrict__ out)
{
  const int row = blockIdx.x * 4 + (threadIdx.x >> 6);
  const int lane = threadIdx.x & 63;
  const int tc = v2s[wsIdx[row]];
  unsigned long long hv = *(const unsigned long long*)(h8 + (size_t)row * H_N + lane * 8);
  const unsigned off = ((unsigned)(lane * 8)) ^ (((unsigned)tc & 15u) << 4);  // un-swizzle
  unsigned long long wv = *(const unsigned long long*)(W2T8 + (size_t)tc * 512 + off);
  float sdot = 0.f;
  #pragma unroll
  for (int j = 0; j < 8; ++j)
    sdot += fp82f((unsigned char)(hv >> (8 * j))) * fp82f((unsigned char)(wv >> (8 * j)));
  #pragma unroll
  for (int k = 32; k >= 1; k >>= 1) sdot += __shfl_xor(sdot, k);
  if (lane == 0) {
    const float tgt = sdot + b2[tc];
    float S = 0.f;
    #pragma unroll
    for (int s = 0; s < NSPLIT; ++s) S += part[(size_t)s * B_N + row].y;
    out[row] = logf(S) - tgt;
  }
}

extern "C" void kernel_launch(void* const* d_in, const int* in_sizes, int n_in,
                              void* d_out, int out_size, void* d_ws, size_t ws_size,
                              hipStream_t stream) {
  const int*   wsIdx   = (const int*)d_in[0];
  const int*   cs      = (const int*)d_in[1];
  const float* vectors = (const float*)d_in[2];
  const float* W1      = (const float*)d_in[3];
  const float* b1      = (const float*)d_in[4];
  const float* W2      = (const float*)d_in[5];
  const float* b2      = (const float*)d_in[6];
  const int*   v2s     = (const int*)d_in[7];

  char* wsb = (char*)d_ws;
  float2* part = (float2*)(wsb + OFF_PART);
  unsigned short* W1T = (unsigned short*)(wsb + OFF_W1T);
  float*  b2l  = (float*)(wsb + OFF_B2L);
  unsigned char* h8   = (unsigned char*)(wsb + OFF_H8);
  char*   W2T8 = wsb + OFF_W2T8;
  float*  out  = (float*)d_out;

  hipLaunchKernelGGL(kprep_a, dim3(120), dim3(256), 0, stream,
                     W1, (unsigned int*)W1T, b2, b2l);
  hipLaunchKernelGGL(kprep_b, dim3(512 + 2560), dim3(256), 0, stream,
                     cs, vectors, W1T, b1, h8, W2, (unsigned long long*)W2T8);
  hipLaunchKernelGGL(k3_fused, dim3((B_N / ROWS_BLK) * NSPLIT), dim3(256), 0, stream,
                     h8, W2T8, b2l, part);
  hipLaunchKernelGGL(k45_final, dim3(B_N / 4), dim3(256), 0, stream,
                     h8, W2T8, b2, wsIdx, v2s, part, out);
}

// Round 10
// 116.818 us; speedup vs baseline: 2.6839x; 2.6839x over previous
//
#include <hip/hip_runtime.h>
#include <hip/hip_bf16.h>
#include <hip/hip_fp8.h>
#include <math.h>

// out[b] = logsumexp_v( relu(vectors[cs[b]]@W1+b1) @ W2 + b2 ) - logit[b, v2s[ws[b]]]
// GEMM2+LSE in MX-scaled fp8 e4m3 K=128 (2x bf16 rate, unit scales); fixed-max
// exp2 LSE (logits bounded ~|4.5|); target dot also fp8 (same quantized operands).
//
// R10: R9's unroll-2 k3 spilled to scratch (FETCH 763MB / WRITE 275MB) -- third
// register-sensitivity blowup (R2/R5/R9); k3 reverted BYTE-FOR-BYTE to the
// verified R7 body (79.9us, MfmaUtil 46, VGPR 64, zero scratch). R9's kprep
// restructure (kprep_a + merged kprep_b: k1 gather co-runs with W2 stream-quant)
// WORKED (non-k3 37.6 -> ~30.5us) and is kept. This round recomposes the two
// verified halves; no new experiments.

typedef __bf16 bf16x8 __attribute__((ext_vector_type(8)));
typedef float f32x4 __attribute__((ext_vector_type(4)));
typedef int i32x4 __attribute__((ext_vector_type(4)));
typedef int i32x8 __attribute__((ext_vector_type(8)));

#define B_N 8192
#define D_N 300
#define K1K 320                // D padded to 10 k-steps of 32
#define H_N 512
#define V_N 20000
#define V_PAD 20480            // 16 splits x 40 chunks x 32 cols
#define NSPLIT 16
#define SPLIT_V 1280           // cols per split
#define NCH 40                 // chunks per split
#define ROWS_BLK 128           // 4 waves x 32 rows (2 m-tiles each)
#define CHUNK_BYTES 16384      // 32 cols x 512 k x 1B (fp8)

#define OFF_PART (8388608u)                        // 16*8192*8 = 1 MB
#define OFF_W1T  (OFF_PART + 16u*8192u*8u)
#define OFF_B2L  (OFF_W1T + 512u*320u*2u)
#define OFF_H8   (OFF_B2L + 20480u*4u)             // 8192*512 = 4 MB
#define OFF_W2T8 (OFF_H8 + 8192u*512u)             // 20480*512 = 10.5 MB

#define SCALE1 0x7F7F7F7F      // E8M0 127 = 2^0 = 1.0 in every byte
#define LOG2E  1.4426950408889634f

__device__ inline unsigned short f2bf(float f) {
  __hip_bfloat16 h = __float2bfloat16(f);
  return *reinterpret_cast<unsigned short*>(&h);
}

__device__ inline unsigned char f2fp8(float f) {
  __hip_fp8_e4m3 q(f);
  return (unsigned char)q.__x;
}

// pack 4 floats -> 4 fp8 e4m3 bytes; HW packed convert where available
__device__ inline unsigned int pk4_fp8(float a, float b, float c, float d) {
#if __has_builtin(__builtin_amdgcn_cvt_pk_fp8_f32)
  int v = 0;
  v = __builtin_amdgcn_cvt_pk_fp8_f32(a, b, v, false);  // bytes 0,1
  v = __builtin_amdgcn_cvt_pk_fp8_f32(c, d, v, true);   // bytes 2,3
  return (unsigned int)v;
#else
  return (unsigned int)f2fp8(a) | ((unsigned int)f2fp8(b) << 8) |
         ((unsigned int)f2fp8(c) << 16) | ((unsigned int)f2fp8(d) << 24);
#endif
}

__device__ inline float fp82f(unsigned char b) {
  __hip_fp8_e4m3 q; q.__x = b;
  return (float)q;
}

__device__ __forceinline__ void gl16(const void* g, void* l) {
  __builtin_amdgcn_global_load_lds(
      (const __attribute__((address_space(1))) void*)g,
      (__attribute__((address_space(3))) void*)l, 16, 0, 0);
}

// ---------------- KPREP_A: W1 transpose (blocks 0..39), b2l (40..119) ----------------
__global__ __launch_bounds__(256) void kprep_a(
    const float* __restrict__ W1, unsigned int* __restrict__ W1Tu,
    const float* __restrict__ b2, float* __restrict__ b2l)
{
  __shared__ float tile[64][65];
  const int bid = blockIdx.x;
  const int tid = threadIdx.x;
  if (bid < 40) {
    // ---- W1 [300][512] f32 -> W1T [512][320] bf16 (k-pad zeros)
    const int n0 = (bid & 7) * 64;   // over H=512
    const int k0 = (bid >> 3) * 64;  // over 320
    #pragma unroll
    for (int it = 0; it < 16; ++it) {
      int idx = it * 256 + tid;
      int i = idx >> 6;     // k-local
      int j = idx & 63;     // n-local
      float v = 0.f;
      if (k0 + i < D_N) v = W1[(size_t)(k0 + i) * H_N + n0 + j];
      tile[i][j] = v;
    }
    __syncthreads();
    #pragma unroll
    for (int it = 0; it < 8; ++it) {
      int idx = it * 256 + tid;
      int nl = idx >> 5;    // 0..63
      int k = (idx & 31) * 2;
      unsigned int lo = f2bf(tile[k][nl]);
      unsigned int hi = f2bf(tile[k + 1][nl]);
      W1Tu[((size_t)(n0 + nl) * K1K + k0 + k) >> 1] = (hi << 16) | lo;
    }
  } else {
    // ---- b2l[i] = i<V_N ? b2[i]*log2e : -3e37 (log2-domain bias, pad -> exp2==0)
    int i = (bid - 40) * 256 + tid;
    if (i < V_PAD) b2l[i] = (i < V_N) ? b2[i] * LOG2E : -3.0e37f;
  }
}

// ---------------- KPREP_B: merged k1 (blocks 0..511) + W2 quant (512..3071) ----------
// k1 (gather/MFMA, latency-bound) and W2 quant (stream-bound) are independent;
// co-scheduling them fills each other's stalls.
__global__ __launch_bounds__(256) void kprep_b(
    const int* __restrict__ cs, const float* __restrict__ vectors,
    const unsigned short* __restrict__ W1T, const float* __restrict__ b1,
    unsigned char* __restrict__ h8Out,
    const float* __restrict__ W2, unsigned long long* __restrict__ W2T8u)
{
  __shared__ float tile[64][65];
  __shared__ __align__(16) unsigned short vca[16][328];
  __shared__ int rowIdx[16];
  const int bid = blockIdx.x;
  const int tid = threadIdx.x;

  if (bid >= 512) {
    // ---- W2 [512][20000] f32 -> W2T8 [20480][512] fp8 (pad rows 0),
    //      PRE-SWIZZLED 16B: byte (n*512 + (k ^ ((n&15)<<4))) holds logical (n,k)
    const int wb = bid - 512;
    const int n0 = (wb >> 3) * 64;
    const int k0 = (wb & 7) * 64;
    #pragma unroll
    for (int it = 0; it < 4; ++it) {
      int idx = it * 256 + tid;        // 0..1023
      int i = idx >> 4;                // k-local 0..63
      int j4 = (idx & 15) * 4;         // n-local 0,4,..,60
      const float* src = &W2[(size_t)(k0 + i) * V_N + n0 + j4];
      float4 v = make_float4(0.f, 0.f, 0.f, 0.f);
      if (n0 + j4 + 3 < V_N) {
        v = *(const float4*)src;
      } else {
        if (n0 + j4 + 0 < V_N) v.x = src[0];
        if (n0 + j4 + 1 < V_N) v.y = src[1];
        if (n0 + j4 + 2 < V_N) v.z = src[2];
        if (n0 + j4 + 3 < V_N) v.w = src[3];
      }
      tile[i][j4 + 0] = v.x; tile[i][j4 + 1] = v.y;
      tile[i][j4 + 2] = v.z; tile[i][j4 + 3] = v.w;
    }
    __syncthreads();
    #pragma unroll
    for (int it = 0; it < 2; ++it) {
      int idx = it * 256 + tid;
      int nl = idx >> 3;          // 0..63
      int g8 = (idx & 7) * 8;     // k-local group start
      int n = n0 + nl;
      unsigned int lo = pk4_fp8(tile[g8 + 0][nl], tile[g8 + 1][nl],
                                tile[g8 + 2][nl], tile[g8 + 3][nl]);
      unsigned int hi = pk4_fp8(tile[g8 + 4][nl], tile[g8 + 5][nl],
                                tile[g8 + 6][nl], tile[g8 + 7][nl]);
      unsigned long long pack = ((unsigned long long)hi << 32) | lo;
      unsigned kk = (unsigned)(k0 + g8);
      unsigned off = ((unsigned)n * 512u + (kk ^ (((unsigned)n & 15u) << 4)));
      W2T8u[off >> 3] = pack;
    }
    return;
  }

  // ---- k1: h = relu(vectors[cs] @ W1 + b1) -> fp8, 16 rows/block ----
  const int lane = tid & 63;
  const int w = tid >> 6;          // wave 0..3 -> col band w*128
  const int l15 = lane & 15;
  const int l4 = lane >> 4;
  const int r0 = bid * 16;
  if (tid < 16) rowIdx[tid] = cs[r0 + tid];
  __syncthreads();
  // div-free staging: float4 gather + ushort4 LDS stores; 82 groups x 4 = 328
  for (int task = tid; task < 16 * 82; task += 256) {
    const int r = task & 15;
    const int g = task >> 4;           // 0..81
    const int k = g * 4;
    float4 v = make_float4(0.f, 0.f, 0.f, 0.f);
    if (k + 3 < D_N)                   // g <= 74 fully in-range
      v = *(const float4*)(vectors + (size_t)rowIdx[r] * D_N + k);
    ushort4 pk;
    pk.x = f2bf(v.x); pk.y = f2bf(v.y); pk.z = f2bf(v.z); pk.w = f2bf(v.w);
    *(ushort4*)&vca[r][k] = pk;
  }
  __syncthreads();

  bf16x8 afr[10];
  #pragma unroll
  for (int t = 0; t < 10; ++t)
    afr[t] = *(const bf16x8*)&vca[l15][t * 32 + l4 * 8];

  f32x4 acc[8];
  #pragma unroll
  for (int ct = 0; ct < 8; ++ct) acc[ct] = (f32x4){0.f, 0.f, 0.f, 0.f};

  #pragma unroll
  for (int t = 0; t < 10; ++t) {
    #pragma unroll
    for (int ct = 0; ct < 8; ++ct) {
      const int n = w * 128 + ct * 16 + l15;
      bf16x8 bfr = *(const bf16x8*)(W1T + (size_t)n * K1K + t * 32 + l4 * 8);
      acc[ct] = __builtin_amdgcn_mfma_f32_16x16x32_bf16(afr[t], bfr, acc[ct], 0, 0, 0);
    }
  }

  #pragma unroll
  for (int ct = 0; ct < 8; ++ct) {
    const int n = w * 128 + ct * 16 + l15;
    const float bb = b1[n];
    #pragma unroll
    for (int r = 0; r < 4; ++r) {
      const int row = r0 + l4 * 4 + r;
      h8Out[(size_t)row * H_N + n] = f2fp8(fmaxf(acc[ct][r] + bb, 0.f));
    }
  }
}

// stage one 16KB fp8 chunk with 256 threads: PURE LINEAR copy (global pre-swizzled)
__device__ __forceinline__ void stage_chunk(const char* g, char* l, int tid) {
  #pragma unroll
  for (int it = 0; it < 4; ++it) {
    const unsigned o = (unsigned)tid * 16 + it * 4096;
    gl16(g + o, l + o);
  }
}

// ---------------- K3: fused MX-fp8 K=128 GEMM2 + fixed-max exp2 LSE ----------------
// grid = 64 rowblocks x 16 splits = 1024 blocks = 4/CU; split = blockIdx&15 ->
// XCD-pinned. 4 waves x 32 rows (2 m-tiles, A = 64 regs) -> 4 waves/SIMD.
// Chunk loop staggered per block (R6, neutral); ct-outer phases w/ interleaved
// epilogue (R3). BYTE-IDENTICAL to the verified R7 body (79.9us) -- R9's
// restructure of this loop spilled to scratch; do not re-touch without asm.
__global__ __launch_bounds__(256, 4) void k3_fused(
    const unsigned char* __restrict__ h8,   // [8192][512] fp8
    const char* __restrict__ W2T8,          // [20480][512] fp8 pre-swizzled (16B XOR)
    const float* __restrict__ b2l,          // [20480] bias*log2e (-3e37 past V_N)
    float2* __restrict__ partOut)
{
  __shared__ __align__(16) char smB[2 * CHUNK_BYTES];  // 32 KB double buffer
  __shared__ float b2s[SPLIT_V];                       // 5 KB bias slice (log2-dom)
  const int tid = threadIdx.x;
  const int lane = tid & 63;
  const int w = tid >> 6;          // wave 0..3
  const int l15 = lane & 15;
  const int l4 = lane >> 4;        // 0..3
  const int s = blockIdx.x & 15;
  const int rb = blockIdx.x >> 4;  // 0..63
  const int r0 = rb * ROWS_BLK + w * 32;
  const char* gsplit = W2T8 + (size_t)s * SPLIT_V * 512;
  const int sCol = s * SPLIT_V;
  // stagger start chunk to decorrelate co-resident blocks (any CU mapping)
  const int c0 = (rb * 7 + s * 3) % NCH;

  // A fragments fp8 K=128 (16x16x128: row=l15, k=l4*32+j): 2 m-tiles x 4 k-steps
  // x 8 regs = 64, full K=512.
  i32x8 afr[2][4];
  #pragma unroll
  for (int m = 0; m < 2; ++m) {
    const unsigned char* ap = h8 + (size_t)(r0 + m * 16 + l15) * H_N + l4 * 32;
    #pragma unroll
    for (int t = 0; t < 4; ++t) {
      i32x4 lo = *(const i32x4*)(ap + t * 128);
      i32x4 hi = *(const i32x4*)(ap + t * 128 + 16);
      afr[m][t] = __builtin_shufflevector(lo, hi, 0, 1, 2, 3, 4, 5, 6, 7);
    }
  }

  // lane-local exp2-sum state (8 rows: 2 m-tiles x 4 regs), fixed max = 0
  float s_run[8];
  #pragma unroll
  for (int ri = 0; ri < 8; ++ri) s_run[ri] = 0.f;

  // bias slice -> LDS
  for (int i = tid; i < SPLIT_V; i += 256) b2s[i] = b2l[sCol + i];

  // prologue: stage chunk c0 into buffer 0
  stage_chunk(gsplit + (size_t)c0 * CHUNK_BYTES, smB, tid);

  const unsigned swz = (unsigned)l15 << 4;   // 16B-granular XOR (matches kprep)

  #pragma unroll 1
  for (int i = 0; i < NCH; ++i) {
    const int cc = (c0 + i >= NCH) ? (c0 + i - NCH) : (c0 + i);
    // drain own staging loads for chunk cc (issued a full chunk ago -> ~free),
    // then barrier so ALL waves' staging (and b2s on i==0) is visible.
    asm volatile("s_waitcnt vmcnt(0) lgkmcnt(0)" ::: "memory");
    __builtin_amdgcn_s_barrier();

    char* cur = smB + (i & 1) * CHUNK_BYTES;
    if (i + 1 < NCH) { // overwrites buffer last read in chunk i-1: safe after barrier
      const int cn = (cc + 1 >= NCH) ? 0 : (cc + 1);
      stage_chunk(gsplit + (size_t)cn * CHUNK_BYTES,
                  smB + ((i & 1) ^ 1) * CHUNK_BYTES, tid);
    }

    const float b2c0 = b2s[cc * 32 + l15];
    const float b2c1 = b2s[cc * 32 + 16 + l15];

    f32x4 acc[2][2];
    #pragma unroll
    for (int m = 0; m < 2; ++m)
      #pragma unroll
      for (int ct = 0; ct < 2; ++ct) acc[m][ct] = (f32x4){0.f, 0.f, 0.f, 0.f};

    // ---- phase 1: ct=0 column tile, full K (2 independent MFMA chains) ----
    #pragma unroll
    for (int t = 0; t < 4; ++t) {
      const char* bp = cur + l15 * 512;
      i32x4 lo = *(const i32x4*)(bp + (((unsigned)(t * 128 + l4 * 32)) ^ swz));
      i32x4 hi = *(const i32x4*)(bp + (((unsigned)(t * 128 + l4 * 32 + 16)) ^ swz));
      i32x8 bfr = __builtin_shufflevector(lo, hi, 0, 1, 2, 3, 4, 5, 6, 7);
      __builtin_amdgcn_s_setprio(1);
      acc[0][0] = __builtin_amdgcn_mfma_scale_f32_16x16x128_f8f6f4(
          afr[0][t], bfr, acc[0][0], 0, 0, 0, SCALE1, 0, SCALE1);
      acc[1][0] = __builtin_amdgcn_mfma_scale_f32_16x16x128_f8f6f4(
          afr[1][t], bfr, acc[1][0], 0, 0, 0, SCALE1, 0, SCALE1);
      __builtin_amdgcn_s_setprio(0);
    }

    // ---- phase 2: ct=1 MFMAs with ct=0 epilogue interleaved (independent) ----
    #pragma unroll
    for (int t = 0; t < 4; ++t) {
      const char* bp = cur + (16 + l15) * 512;
      i32x4 lo = *(const i32x4*)(bp + (((unsigned)(t * 128 + l4 * 32)) ^ swz));
      i32x4 hi = *(const i32x4*)(bp + (((unsigned)(t * 128 + l4 * 32 + 16)) ^ swz));
      i32x8 bfr = __builtin_shufflevector(lo, hi, 0, 1, 2, 3, 4, 5, 6, 7);
      __builtin_amdgcn_s_setprio(1);
      acc[0][1] = __builtin_amdgcn_mfma_scale_f32_16x16x128_f8f6f4(
          afr[0][t], bfr, acc[0][1], 0, 0, 0, SCALE1, 0, SCALE1);
      acc[1][1] = __builtin_amdgcn_mfma_scale_f32_16x16x128_f8f6f4(
          afr[1][t], bfr, acc[1][1], 0, 0, 0, SCALE1, 0, SCALE1);
      __builtin_amdgcn_s_setprio(0);
      // two ct=0 epilogue rows per t-group (independent of in-flight ct=1 MFMAs)
      #pragma unroll
      for (int r2 = 0; r2 < 2; ++r2) {
        const int ri = t * 2 + r2;         // 0..7  -> (m = ri>>2, r = ri&3)
        const int m_ = ri >> 2, r_ = ri & 3;
        s_run[ri] += __builtin_amdgcn_exp2f(fmaf(acc[m_][0][r_], LOG2E, b2c0));
      }
    }

    // ---- phase 3: ct=1 epilogue (short serial tail: 8 exp2) ----
    #pragma unroll
    for (int m = 0; m < 2; ++m)
      #pragma unroll
      for (int r = 0; r < 4; ++r)
        s_run[m * 4 + r] += __builtin_amdgcn_exp2f(fmaf(acc[m][1][r], LOG2E, b2c1));
  }

  // final 16-lane sum merges (once per kernel); stored as (M=0, S)
  #pragma unroll
  for (int m = 0; m < 2; ++m)
    #pragma unroll
    for (int r = 0; r < 4; ++r) {
      int ri = m * 4 + r;
      float sc = s_run[ri];
      #pragma unroll
      for (int k = 1; k < 16; k <<= 1) sc += __shfl_xor(sc, k);
      if (l15 == 0) {
        int grow = r0 + m * 16 + l4 * 4 + r;
        partOut[(size_t)s * B_N + grow] = make_float2(0.f, sc);
      }
    }
}

// ---------------- K45: fp8 target dot (same quantized operands as LSE) + combine ----------------
__global__ __launch_bounds__(256) void k45_final(
    const unsigned char* __restrict__ h8, const char* __restrict__ W2T8,
    const float* __restrict__ b2, const int* __restrict__ wsIdx,
    const int* __restrict__ v2s, const float2* __restrict__ part,
    float* __restrict__ out)
{
  const int row = blockIdx.x * 4 + (threadIdx.x >> 6);
  const int lane = threadIdx.x & 63;
  const int tc = v2s[wsIdx[row]];
  unsigned long long hv = *(const unsigned long long*)(h8 + (size_t)row * H_N + lane * 8);
  const unsigned off = ((unsigned)(lane * 8)) ^ (((unsigned)tc & 15u) << 4);  // un-swizzle
  unsigned long long wv = *(const unsigned long long*)(W2T8 + (size_t)tc * 512 + off);
  float sdot = 0.f;
  #pragma unroll
  for (int j = 0; j < 8; ++j)
    sdot += fp82f((unsigned char)(hv >> (8 * j))) * fp82f((unsigned char)(wv >> (8 * j)));
  #pragma unroll
  for (int k = 32; k >= 1; k >>= 1) sdot += __shfl_xor(sdot, k);
  if (lane == 0) {
    const float tgt = sdot + b2[tc];
    float S = 0.f;
    #pragma unroll
    for (int s = 0; s < NSPLIT; ++s) S += part[(size_t)s * B_N + row].y;
    out[row] = logf(S) - tgt;
  }
}

extern "C" void kernel_launch(void* const* d_in, const int* in_sizes, int n_in,
                              void* d_out, int out_size, void* d_ws, size_t ws_size,
                              hipStream_t stream) {
  const int*   wsIdx   = (const int*)d_in[0];
  const int*   cs      = (const int*)d_in[1];
  const float* vectors = (const float*)d_in[2];
  const float* W1      = (const float*)d_in[3];
  const float* b1      = (const float*)d_in[4];
  const float* W2      = (const float*)d_in[5];
  const float* b2      = (const float*)d_in[6];
  const int*   v2s     = (const int*)d_in[7];

  char* wsb = (char*)d_ws;
  float2* part = (float2*)(wsb + OFF_PART);
  unsigned short* W1T = (unsigned short*)(wsb + OFF_W1T);
  float*  b2l  = (float*)(wsb + OFF_B2L);
  unsigned char* h8   = (unsigned char*)(wsb + OFF_H8);
  char*   W2T8 = wsb + OFF_W2T8;
  float*  out  = (float*)d_out;

  hipLaunchKernelGGL(kprep_a, dim3(120), dim3(256), 0, stream,
                     W1, (unsigned int*)W1T, b2, b2l);
  hipLaunchKernelGGL(kprep_b, dim3(512 + 2560), dim3(256), 0, stream,
                     cs, vectors, W1T, b1, h8, W2, (unsigned long long*)W2T8);
  hipLaunchKernelGGL(k3_fused, dim3((B_N / ROWS_BLK) * NSPLIT), dim3(256), 0, stream,
                     h8, W2T8, b2l, part);
  hipLaunchKernelGGL(k45_final, dim3(B_N / 4), dim3(256), 0, stream,
                     h8, W2T8, b2, wsIdx, v2s, part, out);
}

// Round 11
// 114.588 us; speedup vs baseline: 2.7362x; 1.0195x over previous
//
#include <hip/hip_runtime.h>
#include <hip/hip_bf16.h>
#include <hip/hip_fp8.h>
#include <math.h>

// out[b] = logsumexp_v( relu(vectors[cs[b]]@W1+b1) @ W2 + b2 ) - logit[b, v2s[ws[b]]]
// GEMM2+LSE in MX-scaled fp8 e4m3 K=128 (2x bf16 rate, unit scales); fixed-max
// exp2 LSE (logits bounded ~|4.5|); target dot also fp8 (same quantized operands).
//
// R11: k3's GEMM loop FROZEN (R7 body; 3 restructures spilled -- R2/R9; B-path
// changes regressed -- R1/R4/R5/R8; it is a balanced MFMA-46/LDS-63/VALU-41
// basin, register-capped at 16 waves/CU). This round harvests graph-level wins:
// the target dot (h8 . W2T8[tc]) depends only on kprep_b outputs, NOT on part,
// so it is folded into k3's grid as 256 LEADING blocks -- it runs and finishes
// inside k3's 80us shadow. part becomes row-major plain float ([row][16], 64B
// contiguous) so the combine kernel (k45b) is a trivial coalesced 32-block pass.

typedef __bf16 bf16x8 __attribute__((ext_vector_type(8)));
typedef float f32x4 __attribute__((ext_vector_type(4)));
typedef int i32x4 __attribute__((ext_vector_type(4)));
typedef int i32x8 __attribute__((ext_vector_type(8)));

#define B_N 8192
#define D_N 300
#define K1K 320                // D padded to 10 k-steps of 32
#define H_N 512
#define V_N 20000
#define V_PAD 20480            // 16 splits x 40 chunks x 32 cols
#define NSPLIT 16
#define SPLIT_V 1280           // cols per split
#define NCH 40                 // chunks per split
#define ROWS_BLK 128           // 4 waves x 32 rows (2 m-tiles each)
#define CHUNK_BYTES 16384      // 32 cols x 512 k x 1B (fp8)
#define TGT_BLKS 256           // leading k3 blocks doing the target dot (32 rows each)

#define OFF_PART (8388608u)                        // part [8192][16] f32 = 512 KB
#define OFF_TGT  (OFF_PART + 8192u*16u*4u)         // tgt  [8192] f32 = 32 KB
#define OFF_W1T  (OFF_PART + 16u*8192u*8u)
#define OFF_B2L  (OFF_W1T + 512u*320u*2u)
#define OFF_H8   (OFF_B2L + 20480u*4u)             // 8192*512 = 4 MB
#define OFF_W2T8 (OFF_H8 + 8192u*512u)             // 20480*512 = 10.5 MB

#define SCALE1 0x7F7F7F7F      // E8M0 127 = 2^0 = 1.0 in every byte
#define LOG2E  1.4426950408889634f

__device__ inline unsigned short f2bf(float f) {
  __hip_bfloat16 h = __float2bfloat16(f);
  return *reinterpret_cast<unsigned short*>(&h);
}

__device__ inline unsigned char f2fp8(float f) {
  __hip_fp8_e4m3 q(f);
  return (unsigned char)q.__x;
}

// pack 4 floats -> 4 fp8 e4m3 bytes; HW packed convert where available
__device__ inline unsigned int pk4_fp8(float a, float b, float c, float d) {
#if __has_builtin(__builtin_amdgcn_cvt_pk_fp8_f32)
  int v = 0;
  v = __builtin_amdgcn_cvt_pk_fp8_f32(a, b, v, false);  // bytes 0,1
  v = __builtin_amdgcn_cvt_pk_fp8_f32(c, d, v, true);   // bytes 2,3
  return (unsigned int)v;
#else
  return (unsigned int)f2fp8(a) | ((unsigned int)f2fp8(b) << 8) |
         ((unsigned int)f2fp8(c) << 16) | ((unsigned int)f2fp8(d) << 24);
#endif
}

__device__ inline float fp82f(unsigned char b) {
  __hip_fp8_e4m3 q; q.__x = b;
  return (float)q;
}

__device__ __forceinline__ void gl16(const void* g, void* l) {
  __builtin_amdgcn_global_load_lds(
      (const __attribute__((address_space(1))) void*)g,
      (__attribute__((address_space(3))) void*)l, 16, 0, 0);
}

// ---------------- KPREP_A: W1 transpose (blocks 0..39), b2l (40..119) ----------------
__global__ __launch_bounds__(256) void kprep_a(
    const float* __restrict__ W1, unsigned int* __restrict__ W1Tu,
    const float* __restrict__ b2, float* __restrict__ b2l)
{
  __shared__ float tile[64][65];
  const int bid = blockIdx.x;
  const int tid = threadIdx.x;
  if (bid < 40) {
    // ---- W1 [300][512] f32 -> W1T [512][320] bf16 (k-pad zeros)
    const int n0 = (bid & 7) * 64;   // over H=512
    const int k0 = (bid >> 3) * 64;  // over 320
    #pragma unroll
    for (int it = 0; it < 16; ++it) {
      int idx = it * 256 + tid;
      int i = idx >> 6;     // k-local
      int j = idx & 63;     // n-local
      float v = 0.f;
      if (k0 + i < D_N) v = W1[(size_t)(k0 + i) * H_N + n0 + j];
      tile[i][j] = v;
    }
    __syncthreads();
    #pragma unroll
    for (int it = 0; it < 8; ++it) {
      int idx = it * 256 + tid;
      int nl = idx >> 5;    // 0..63
      int k = (idx & 31) * 2;
      unsigned int lo = f2bf(tile[k][nl]);
      unsigned int hi = f2bf(tile[k + 1][nl]);
      W1Tu[((size_t)(n0 + nl) * K1K + k0 + k) >> 1] = (hi << 16) | lo;
    }
  } else {
    // ---- b2l[i] = i<V_N ? b2[i]*log2e : -3e37 (log2-domain bias, pad -> exp2==0)
    int i = (bid - 40) * 256 + tid;
    if (i < V_PAD) b2l[i] = (i < V_N) ? b2[i] * LOG2E : -3.0e37f;
  }
}

// ---------------- KPREP_B: merged k1 (blocks 0..511) + W2 quant (512..3071) ----------
// k1 (gather/MFMA, latency-bound) and W2 quant (stream-bound) are independent;
// co-scheduling them fills each other's stalls.
__global__ __launch_bounds__(256) void kprep_b(
    const int* __restrict__ cs, const float* __restrict__ vectors,
    const unsigned short* __restrict__ W1T, const float* __restrict__ b1,
    unsigned char* __restrict__ h8Out,
    const float* __restrict__ W2, unsigned long long* __restrict__ W2T8u)
{
  __shared__ float tile[64][65];
  __shared__ __align__(16) unsigned short vca[16][328];
  __shared__ int rowIdx[16];
  const int bid = blockIdx.x;
  const int tid = threadIdx.x;

  if (bid >= 512) {
    // ---- W2 [512][20000] f32 -> W2T8 [20480][512] fp8 (pad rows 0),
    //      PRE-SWIZZLED 16B: byte (n*512 + (k ^ ((n&15)<<4))) holds logical (n,k)
    const int wb = bid - 512;
    const int n0 = (wb >> 3) * 64;
    const int k0 = (wb & 7) * 64;
    #pragma unroll
    for (int it = 0; it < 4; ++it) {
      int idx = it * 256 + tid;        // 0..1023
      int i = idx >> 4;                // k-local 0..63
      int j4 = (idx & 15) * 4;         // n-local 0,4,..,60
      const float* src = &W2[(size_t)(k0 + i) * V_N + n0 + j4];
      float4 v = make_float4(0.f, 0.f, 0.f, 0.f);
      if (n0 + j4 + 3 < V_N) {
        v = *(const float4*)src;
      } else {
        if (n0 + j4 + 0 < V_N) v.x = src[0];
        if (n0 + j4 + 1 < V_N) v.y = src[1];
        if (n0 + j4 + 2 < V_N) v.z = src[2];
        if (n0 + j4 + 3 < V_N) v.w = src[3];
      }
      tile[i][j4 + 0] = v.x; tile[i][j4 + 1] = v.y;
      tile[i][j4 + 2] = v.z; tile[i][j4 + 3] = v.w;
    }
    __syncthreads();
    #pragma unroll
    for (int it = 0; it < 2; ++it) {
      int idx = it * 256 + tid;
      int nl = idx >> 3;          // 0..63
      int g8 = (idx & 7) * 8;     // k-local group start
      int n = n0 + nl;
      unsigned int lo = pk4_fp8(tile[g8 + 0][nl], tile[g8 + 1][nl],
                                tile[g8 + 2][nl], tile[g8 + 3][nl]);
      unsigned int hi = pk4_fp8(tile[g8 + 4][nl], tile[g8 + 5][nl],
                                tile[g8 + 6][nl], tile[g8 + 7][nl]);
      unsigned long long pack = ((unsigned long long)hi << 32) | lo;
      unsigned kk = (unsigned)(k0 + g8);
      unsigned off = ((unsigned)n * 512u + (kk ^ (((unsigned)n & 15u) << 4)));
      W2T8u[off >> 3] = pack;
    }
    return;
  }

  // ---- k1: h = relu(vectors[cs] @ W1 + b1) -> fp8, 16 rows/block ----
  const int lane = tid & 63;
  const int w = tid >> 6;          // wave 0..3 -> col band w*128
  const int l15 = lane & 15;
  const int l4 = lane >> 4;
  const int r0 = bid * 16;
  if (tid < 16) rowIdx[tid] = cs[r0 + tid];
  __syncthreads();
  // div-free staging: float4 gather + ushort4 LDS stores; 82 groups x 4 = 328
  for (int task = tid; task < 16 * 82; task += 256) {
    const int r = task & 15;
    const int g = task >> 4;           // 0..81
    const int k = g * 4;
    float4 v = make_float4(0.f, 0.f, 0.f, 0.f);
    if (k + 3 < D_N)                   // g <= 74 fully in-range
      v = *(const float4*)(vectors + (size_t)rowIdx[r] * D_N + k);
    ushort4 pk;
    pk.x = f2bf(v.x); pk.y = f2bf(v.y); pk.z = f2bf(v.z); pk.w = f2bf(v.w);
    *(ushort4*)&vca[r][k] = pk;
  }
  __syncthreads();

  bf16x8 afr[10];
  #pragma unroll
  for (int t = 0; t < 10; ++t)
    afr[t] = *(const bf16x8*)&vca[l15][t * 32 + l4 * 8];

  f32x4 acc[8];
  #pragma unroll
  for (int ct = 0; ct < 8; ++ct) acc[ct] = (f32x4){0.f, 0.f, 0.f, 0.f};

  #pragma unroll
  for (int t = 0; t < 10; ++t) {
    #pragma unroll
    for (int ct = 0; ct < 8; ++ct) {
      const int n = w * 128 + ct * 16 + l15;
      bf16x8 bfr = *(const bf16x8*)(W1T + (size_t)n * K1K + t * 32 + l4 * 8);
      acc[ct] = __builtin_amdgcn_mfma_f32_16x16x32_bf16(afr[t], bfr, acc[ct], 0, 0, 0);
    }
  }

  #pragma unroll
  for (int ct = 0; ct < 8; ++ct) {
    const int n = w * 128 + ct * 16 + l15;
    const float bb = b1[n];
    #pragma unroll
    for (int r = 0; r < 4; ++r) {
      const int row = r0 + l4 * 4 + r;
      h8Out[(size_t)row * H_N + n] = f2fp8(fmaxf(acc[ct][r] + bb, 0.f));
    }
  }
}

// stage one 16KB fp8 chunk with 256 threads: PURE LINEAR copy (global pre-swizzled)
__device__ __forceinline__ void stage_chunk(const char* g, char* l, int tid) {
  #pragma unroll
  for (int it = 0; it < 4; ++it) {
    const unsigned o = (unsigned)tid * 16 + it * 4096;
    gl16(g + o, l + o);
  }
}

// ---------------- K3: fused MX-fp8 K=128 GEMM2 + fixed-max exp2 LSE,
//                  plus TGT_BLKS leading blocks computing the target dot ---------------
// Blocks 0..255: tgt[row] = h8[row] . W2T8[tc] + b2[tc]  (32 rows/block, 8 lanes/row)
//   -- depends only on kprep_b outputs; runs inside the GEMM's 80us shadow.
// Blocks 256..1279: the FROZEN R7 GEMM+LSE body (79.9us verified; 3 restructures
//   spilled -- do not re-touch without asm). part now [row][16] plain float.
__global__ __launch_bounds__(256, 4) void k3_fused(
    const unsigned char* __restrict__ h8,   // [8192][512] fp8
    const char* __restrict__ W2T8,          // [20480][512] fp8 pre-swizzled (16B XOR)
    const float* __restrict__ b2l,          // [20480] bias*log2e (-3e37 past V_N)
    const float* __restrict__ b2,           // [20000] raw bias (tgt path)
    const int* __restrict__ wsIdx, const int* __restrict__ v2s,
    float* __restrict__ partOut,            // [8192][16] f32
    float* __restrict__ tgtOut)             // [8192] f32
{
  __shared__ __align__(16) char smB[2 * CHUNK_BYTES];  // 32 KB double buffer
  __shared__ float b2s[SPLIT_V];                       // 5 KB bias slice (log2-dom)
  const int tid = threadIdx.x;

  if (blockIdx.x < TGT_BLKS) {
    // ---- target dot: row = bid*32 + tid>>3; lane j = tid&7 covers bytes j*64..+63
    const int row = blockIdx.x * 32 + (tid >> 3);
    const int j = tid & 7;
    const int tc = v2s[wsIdx[row]];
    const unsigned swzt = ((unsigned)tc & 15u) << 4;
    const unsigned char* hp = h8 + (size_t)row * H_N + j * 64;
    const char* wp = W2T8 + (size_t)tc * 512;
    float sdot = 0.f;
    #pragma unroll
    for (int q = 0; q < 8; ++q) {
      unsigned long long hv = *(const unsigned long long*)(hp + q * 8);
      const unsigned k8 = (unsigned)(j * 64 + q * 8);
      unsigned long long wv = *(const unsigned long long*)(wp + (k8 ^ swzt));
      #pragma unroll
      for (int b = 0; b < 8; ++b)
        sdot += fp82f((unsigned char)(hv >> (8 * b))) *
                fp82f((unsigned char)(wv >> (8 * b)));
    }
    #pragma unroll
    for (int k = 1; k < 8; k <<= 1) sdot += __shfl_xor(sdot, k);
    if (j == 0) tgtOut[row] = sdot + b2[tc];
    return;
  }

  // ---------------- FROZEN R7 GEMM+LSE body ----------------
  const int bid = blockIdx.x - TGT_BLKS;
  const int lane = tid & 63;
  const int w = tid >> 6;          // wave 0..3
  const int l15 = lane & 15;
  const int l4 = lane >> 4;        // 0..3
  const int s = bid & 15;
  const int rb = bid >> 4;         // 0..63
  const int r0 = rb * ROWS_BLK + w * 32;
  const char* gsplit = W2T8 + (size_t)s * SPLIT_V * 512;
  const int sCol = s * SPLIT_V;
  // stagger start chunk to decorrelate co-resident blocks (any CU mapping)
  const int c0 = (rb * 7 + s * 3) % NCH;

  // A fragments fp8 K=128 (16x16x128: row=l15, k=l4*32+j): 2 m-tiles x 4 k-steps
  // x 8 regs = 64, full K=512.
  i32x8 afr[2][4];
  #pragma unroll
  for (int m = 0; m < 2; ++m) {
    const unsigned char* ap = h8 + (size_t)(r0 + m * 16 + l15) * H_N + l4 * 32;
    #pragma unroll
    for (int t = 0; t < 4; ++t) {
      i32x4 lo = *(const i32x4*)(ap + t * 128);
      i32x4 hi = *(const i32x4*)(ap + t * 128 + 16);
      afr[m][t] = __builtin_shufflevector(lo, hi, 0, 1, 2, 3, 4, 5, 6, 7);
    }
  }

  // lane-local exp2-sum state (8 rows: 2 m-tiles x 4 regs), fixed max = 0
  float s_run[8];
  #pragma unroll
  for (int ri = 0; ri < 8; ++ri) s_run[ri] = 0.f;

  // bias slice -> LDS
  for (int i = tid; i < SPLIT_V; i += 256) b2s[i] = b2l[sCol + i];

  // prologue: stage chunk c0 into buffer 0
  stage_chunk(gsplit + (size_t)c0 * CHUNK_BYTES, smB, tid);

  const unsigned swz = (unsigned)l15 << 4;   // 16B-granular XOR (matches kprep)

  #pragma unroll 1
  for (int i = 0; i < NCH; ++i) {
    const int cc = (c0 + i >= NCH) ? (c0 + i - NCH) : (c0 + i);
    // drain own staging loads for chunk cc (issued a full chunk ago -> ~free),
    // then barrier so ALL waves' staging (and b2s on i==0) is visible.
    asm volatile("s_waitcnt vmcnt(0) lgkmcnt(0)" ::: "memory");
    __builtin_amdgcn_s_barrier();

    char* cur = smB + (i & 1) * CHUNK_BYTES;
    if (i + 1 < NCH) { // overwrites buffer last read in chunk i-1: safe after barrier
      const int cn = (cc + 1 >= NCH) ? 0 : (cc + 1);
      stage_chunk(gsplit + (size_t)cn * CHUNK_BYTES,
                  smB + ((i & 1) ^ 1) * CHUNK_BYTES, tid);
    }

    const float b2c0 = b2s[cc * 32 + l15];
    const float b2c1 = b2s[cc * 32 + 16 + l15];

    f32x4 acc[2][2];
    #pragma unroll
    for (int m = 0; m < 2; ++m)
      #pragma unroll
      for (int ct = 0; ct < 2; ++ct) acc[m][ct] = (f32x4){0.f, 0.f, 0.f, 0.f};

    // ---- phase 1: ct=0 column tile, full K (2 independent MFMA chains) ----
    #pragma unroll
    for (int t = 0; t < 4; ++t) {
      const char* bp = cur + l15 * 512;
      i32x4 lo = *(const i32x4*)(bp + (((unsigned)(t * 128 + l4 * 32)) ^ swz));
      i32x4 hi = *(const i32x4*)(bp + (((unsigned)(t * 128 + l4 * 32 + 16)) ^ swz));
      i32x8 bfr = __builtin_shufflevector(lo, hi, 0, 1, 2, 3, 4, 5, 6, 7);
      __builtin_amdgcn_s_setprio(1);
      acc[0][0] = __builtin_amdgcn_mfma_scale_f32_16x16x128_f8f6f4(
          afr[0][t], bfr, acc[0][0], 0, 0, 0, SCALE1, 0, SCALE1);
      acc[1][0] = __builtin_amdgcn_mfma_scale_f32_16x16x128_f8f6f4(
          afr[1][t], bfr, acc[1][0], 0, 0, 0, SCALE1, 0, SCALE1);
      __builtin_amdgcn_s_setprio(0);
    }

    // ---- phase 2: ct=1 MFMAs with ct=0 epilogue interleaved (independent) ----
    #pragma unroll
    for (int t = 0; t < 4; ++t) {
      const char* bp = cur + (16 + l15) * 512;
      i32x4 lo = *(const i32x4*)(bp + (((unsigned)(t * 128 + l4 * 32)) ^ swz));
      i32x4 hi = *(const i32x4*)(bp + (((unsigned)(t * 128 + l4 * 32 + 16)) ^ swz));
      i32x8 bfr = __builtin_shufflevector(lo, hi, 0, 1, 2, 3, 4, 5, 6, 7);
      __builtin_amdgcn_s_setprio(1);
      acc[0][1] = __builtin_amdgcn_mfma_scale_f32_16x16x128_f8f6f4(
          afr[0][t], bfr, acc[0][1], 0, 0, 0, SCALE1, 0, SCALE1);
      acc[1][1] = __builtin_amdgcn_mfma_scale_f32_16x16x128_f8f6f4(
          afr[1][t], bfr, acc[1][1], 0, 0, 0, SCALE1, 0, SCALE1);
      __builtin_amdgcn_s_setprio(0);
      // two ct=0 epilogue rows per t-group (independent of in-flight ct=1 MFMAs)
      #pragma unroll
      for (int r2 = 0; r2 < 2; ++r2) {
        const int ri = t * 2 + r2;         // 0..7  -> (m = ri>>2, r = ri&3)
        const int m_ = ri >> 2, r_ = ri & 3;
        s_run[ri] += __builtin_amdgcn_exp2f(fmaf(acc[m_][0][r_], LOG2E, b2c0));
      }
    }

    // ---- phase 3: ct=1 epilogue (short serial tail: 8 exp2) ----
    #pragma unroll
    for (int m = 0; m < 2; ++m)
      #pragma unroll
      for (int r = 0; r < 4; ++r)
        s_run[m * 4 + r] += __builtin_amdgcn_exp2f(fmaf(acc[m][1][r], LOG2E, b2c1));
  }

  // final 16-lane sum merges (once per kernel); part layout [row][split]
  #pragma unroll
  for (int m = 0; m < 2; ++m)
    #pragma unroll
    for (int r = 0; r < 4; ++r) {
      int ri = m * 4 + r;
      float sc = s_run[ri];
      #pragma unroll
      for (int k = 1; k < 16; k <<= 1) sc += __shfl_xor(sc, k);
      if (l15 == 0) {
        int grow = r0 + m * 16 + l4 * 4 + r;
        partOut[(size_t)grow * NSPLIT + s] = sc;
      }
    }
}

// ---------------- K45B: out[row] = log(sum_s part[row][s]) - tgt[row] ----------------
__global__ __launch_bounds__(256) void k45b_final(
    const float* __restrict__ part, const float* __restrict__ tgt,
    float* __restrict__ out)
{
  const int row = blockIdx.x * 256 + threadIdx.x;
  const f32x4* p = (const f32x4*)(part + (size_t)row * NSPLIT);
  f32x4 a = p[0], b = p[1], c = p[2], d = p[3];
  float S = (a[0] + a[1] + a[2] + a[3]) + (b[0] + b[1] + b[2] + b[3]) +
            (c[0] + c[1] + c[2] + c[3]) + (d[0] + d[1] + d[2] + d[3]);
  out[row] = logf(S) - tgt[row];
}

extern "C" void kernel_launch(void* const* d_in, const int* in_sizes, int n_in,
                              void* d_out, int out_size, void* d_ws, size_t ws_size,
                              hipStream_t stream) {
  const int*   wsIdx   = (const int*)d_in[0];
  const int*   cs      = (const int*)d_in[1];
  const float* vectors = (const float*)d_in[2];
  const float* W1      = (const float*)d_in[3];
  const float* b1      = (const float*)d_in[4];
  const float* W2      = (const float*)d_in[5];
  const float* b2      = (const float*)d_in[6];
  const int*   v2s     = (const int*)d_in[7];

  char* wsb = (char*)d_ws;
  float*  part = (float*)(wsb + OFF_PART);
  float*  tgt  = (float*)(wsb + OFF_TGT);
  unsigned short* W1T = (unsigned short*)(wsb + OFF_W1T);
  float*  b2l  = (float*)(wsb + OFF_B2L);
  unsigned char* h8   = (unsigned char*)(wsb + OFF_H8);
  char*   W2T8 = wsb + OFF_W2T8;
  float*  out  = (float*)d_out;

  hipLaunchKernelGGL(kprep_a, dim3(120), dim3(256), 0, stream,
                     W1, (unsigned int*)W1T, b2, b2l);
  hipLaunchKernelGGL(kprep_b, dim3(512 + 2560), dim3(256), 0, stream,
                     cs, vectors, W1T, b1, h8, W2, (unsigned long long*)W2T8);
  hipLaunchKernelGGL(k3_fused, dim3(TGT_BLKS + (B_N / ROWS_BLK) * NSPLIT), dim3(256),
                     0, stream, h8, W2T8, b2l, b2, wsIdx, v2s, part, tgt);
  hipLaunchKernelGGL(k45b_final, dim3(B_N / 256), dim3(256), 0, stream,
                     part, tgt, out);
}